// Round 1
// baseline (34345.343 us; speedup 1.0000x reference)
//
#include <hip/hip_runtime.h>
#include <math.h>

#define B_TOT 16384
#define CC 7
#define CELLS 36
#define YDIM 252      // C*G*G
#define FEAT_DIM 416  // 252 + 36 + 128
#define HDIM 2048
#define EMB_DIM 128
#define KSTEPS 50

__device__ __forceinline__ float clip01(float x){ return fminf(fmaxf(x, 0.f), 1.f); }

// jax.nn.gelu approximate=True
__device__ __forceinline__ float gelu_f(float x){
  float u = 0.7978845608028654f * (x + 0.044715f * x * x * x);
  return 0.5f * x * (1.f + tanhf(u));
}
__device__ __forceinline__ float dgelu_f(float x){
  float x2 = x * x;
  float u = 0.7978845608028654f * (x + 0.044715f * x2 * x);
  float t = tanhf(u);
  return 0.5f * (1.f + t) + 0.5f * x * (1.f - t * t) * 0.7978845608028654f * (1.f + 0.134145f * x2);
}
// JAX clip(x,0,1) gradient: 0.5 at exact boundary (balanced_eq tie), 1 inside.
__device__ __forceinline__ float clipmask(float y){ return (y == 0.f || y == 1.f) ? 0.5f : 1.f; }

// ---------------- small kernels ----------------
__global__ void k_zero_acc(double* acc){ acc[0] = 0.0; acc[1] = 0.0; acc[2] = 0.0; }

__global__ void k_sigma(const int* __restrict__ k_idx, float* __restrict__ sigma_b){
  int b = blockIdx.x * blockDim.x + threadIdx.x;
  if (b >= B_TOT) return;
  int i = (KSTEPS - 1) - k_idx[b];           // reversed schedule
  float t = (float)i / (float)(KSTEPS - 1);
  float ang = (1.f - t) * 1.57079632679489662f;
  float c = cosf(ang);
  sigma_b[b] = 0.01f + 0.94f * c * c;
}

// _add_probability_noise: one thread per (sample,cell). y,eps,sigma_b are chunk-offset.
__global__ void k_noise(const float* __restrict__ y, const float* __restrict__ eps,
                        const float* __restrict__ sigma_b, float* __restrict__ out, int Mc){
  int gid = blockIdx.x * blockDim.x + threadIdx.x;
  if (gid >= Mc * CELLS) return;
  int i = gid / CELLS, cell = gid - i * CELLS;
  float sigma = sigma_b[i];
  float sq = sqrtf(fmaxf(1.f - sigma * sigma, 1e-8f));
  const float* yp = y + (size_t)i * YDIM + cell;
  const float* ep = eps + (size_t)i * YDIM + cell;
  float yh[CC];
#pragma unroll
  for (int ch = 0; ch < CC; ++ch){
    float e = ep[ch * CELLS] * 0.1f;                // eps_raw * EPS_PROB
    yh[ch] = clip01(sq * yp[ch * CELLS] + sigma * e);
  }
  bool filled = yh[0] > 0.5f;
  float s = 0.f;
#pragma unroll
  for (int ch = 1; ch < CC; ++ch) s += yh[ch];
  float* op = out + (size_t)i * YDIM + cell;
  op[0] = yh[0];
#pragma unroll
  for (int ch = 1; ch < CC; ++ch){
    float v = yh[ch];
    if (filled) v = v / (s + 1e-8f);
    op[ch * CELLS] = clip01(v);
  }
}

// feat = [clip(y), cond, k_emb[k_idx]]; cond/k_idx chunk-offset, ysrc chunk-local.
__global__ void k_feat(const float* __restrict__ ysrc, const float* __restrict__ cond,
                       const float* __restrict__ k_emb, const int* __restrict__ k_idx,
                       float* __restrict__ feat, int Mc){
  int gid = blockIdx.x * blockDim.x + threadIdx.x;
  if (gid >= Mc * FEAT_DIM) return;
  int i = gid / FEAT_DIM, c = gid - i * FEAT_DIM;
  float v;
  if (c < YDIM)              v = clip01(ysrc[(size_t)i * YDIM + c]);
  else if (c < YDIM + CELLS) v = cond[(size_t)i * CELLS + (c - YDIM)];
  else                       v = k_emb[(size_t)k_idx[i] * EMB_DIM + (c - YDIM - CELLS)];
  feat[gid] = v;
}

__global__ void k_gelu(const float* __restrict__ z, float* __restrict__ h, int n){
  int gid = blockIdx.x * blockDim.x + threadIdx.x;
  if (gid < n) h[gid] = gelu_f(z[gid]);
}

// dz2 = W3[j] * gelu'(z2)
__global__ void k_dz2(const float* __restrict__ z2, const float* __restrict__ W3,
                      float* __restrict__ dz2, int n){
  int gid = blockIdx.x * blockDim.x + threadIdx.x;
  if (gid >= n) return;
  int j = gid & (HDIM - 1);
  dz2[gid] = W3[j] * dgelu_f(z2[gid]);
}

// e = sum_j gelu(z2[j])*W3[j] + b3 : one wave per row
__global__ void k_energy(const float* __restrict__ z2, const float* __restrict__ W3,
                         const float* __restrict__ b3, float* __restrict__ e_out, int Mc){
  int wv = (blockIdx.x * blockDim.x + threadIdx.x) >> 6;
  int lane = threadIdx.x & 63;
  if (wv >= Mc) return;
  const float* z = z2 + (size_t)wv * HDIM;
  float s = 0.f;
  for (int j = lane; j < HDIM; j += 64) s += gelu_f(z[j]) * W3[j];
  for (int off = 32; off; off >>= 1) s += __shfl_down(s, off);
  if (lane == 0) e_out[wv] = s + b3[0];
}

// y_neg init (_make_negative pre-refine): one wave per sample.
__global__ void k_makeneg(const float* __restrict__ y_true, const float* __restrict__ sel,
                          const float* __restrict__ rv, float* __restrict__ y_neg,
                          int b0, int Mc){
  int w = (blockIdx.x * blockDim.x + threadIdx.x) >> 6;
  int lane = threadIdx.x & 63;
  if (w >= Mc) return;
  int b = b0 + w;
  int c = lane;
  bool active = c < CELLS;
  float yt0 = active ? y_true[(size_t)b * YDIM + c] : 0.f;
  bool filled = active && (yt0 > 0.5f);
  unsigned long long bal = __ballot(filled);
  int n_filled = __popcll(bal);
  int num_c = (int)floorf((float)n_filled * 0.3f);
  int idx = num_c - 1; if (idx < 0) idx = 0;
  float score = filled ? sel[(size_t)b * CELLS + c] : 2.0f;
  int cnt_lt = 0, cnt_le = 0;
  for (int l = 0; l < CELLS; ++l){
    float sv = __shfl(score, l);
    cnt_lt += (sv < score);
    cnt_le += (sv <= score);
  }
  float cand = (active && cnt_lt <= idx && idx < cnt_le) ? score : 3.4e38f;
  for (int off = 32; off; off >>= 1) cand = fminf(cand, __shfl_xor(cand, off));
  float thr = (num_c > 0) ? cand : -1.0f;
  bool corrupt = filled && (score <= thr);
  if (active){
    float rvv[6]; float rsum = 0.f;
#pragma unroll
    for (int ch = 0; ch < 6; ++ch){ rvv[ch] = rv[(size_t)b * (6 * CELLS) + ch * CELLS + c]; rsum += rvv[ch]; }
    y_neg[(size_t)w * YDIM + c] = corrupt ? 0.f : yt0;
#pragma unroll
    for (int ch = 0; ch < 6; ++ch){
      float val = corrupt ? rvv[ch] / rsum : y_true[(size_t)b * YDIM + (ch + 1) * CELLS + c];
      y_neg[(size_t)w * YDIM + (ch + 1) * CELLS + c] = val;
    }
  }
}

// refine update: y = clip(y + LR * dy * clipmask(y), 0, 1)
__global__ void k_update(float* __restrict__ y_neg, const float* __restrict__ dy, int n){
  int gid = blockIdx.x * blockDim.x + threadIdx.x;
  if (gid >= n) return;
  float y = y_neg[gid];
  float g = dy[gid] * clipmask(y);
  y_neg[gid] = clip01(y + 0.15f * g);
}

// mse accumulation: sum (dy*mask - (yhat - y_true)/(sigma+1e-8))^2
__global__ void k_mse(const float* __restrict__ dy, const float* __restrict__ yhat,
                      const float* __restrict__ y_true, const float* __restrict__ sigma_b,
                      double* __restrict__ acc, int Mc){
  int gid = blockIdx.x * blockDim.x + threadIdx.x;
  double v = 0.0;
  if (gid < Mc * YDIM){
    int i = gid / YDIM;
    float y = yhat[gid];
    float score = dy[gid] * clipmask(y);
    float sigma = sigma_b[i];
    float tgt = (y - y_true[gid]) / (sigma + 1e-8f);
    float d = score - tgt;
    v = (double)d * (double)d;
  }
  for (int off = 32; off; off >>= 1) v += __shfl_down(v, off);
  if ((threadIdx.x & 63) == 0) atomicAdd(&acc[0], v);
}

__global__ void k_contrast(const float* __restrict__ e_pos, const float* __restrict__ e_neg,
                           double* __restrict__ acc){
  int b = blockIdx.x * blockDim.x + threadIdx.x;
  double con = 0.0, reg = 0.0;
  if (b < B_TOT){
    float ep = e_pos[b], en = e_neg[b];
    float a = -ep, bb = -en;
    float m = fmaxf(a, bb);
    float lse = m + logf(expf(a - m) + expf(bb - m));
    con = (double)(ep + lse);
    reg = (double)ep + (double)en;
  }
  for (int off = 32; off; off >>= 1){ con += __shfl_down(con, off); reg += __shfl_down(reg, off); }
  if ((threadIdx.x & 63) == 0){ atomicAdd(&acc[1], con); atomicAdd(&acc[2], reg); }
}

__global__ void k_finalize(const double* __restrict__ acc, float* __restrict__ out){
  double mse = acc[0] / (double)((long long)B_TOT * YDIM);
  double con = acc[1] / (double)B_TOT;
  double reg = acc[2] / (double)B_TOT;
  out[0] = (float)(mse + con + 0.01 * reg);
}

// ---------------- GEMMs (fp32, 64x64x16 tile, 4x4 microtile) ----------------
// C[M,N] = A[M,K] @ B[K,N] (+ bias). M%64==0, K%16==0. N guarded.
__global__ __launch_bounds__(256) void gemm_nn(const float* __restrict__ A, const float* __restrict__ Bm,
                                               const float* __restrict__ bias, float* __restrict__ C,
                                               int M, int N, int Kd){
  __shared__ __align__(16) float As[16][68];
  __shared__ __align__(16) float Bs[16][68];
  int t = threadIdx.x;
  int tx = t & 15, ty = t >> 4;
  int m0 = blockIdx.y << 6, n0 = blockIdx.x << 6;
  float acc[4][4] = {};
  for (int k0 = 0; k0 < Kd; k0 += 16){
    {   // A tile: float4 along k per thread
      int r = t >> 2, kq = (t & 3) << 2;
      float4 v = *reinterpret_cast<const float4*>(&A[(size_t)(m0 + r) * Kd + (k0 + kq)]);
      As[kq + 0][r] = v.x; As[kq + 1][r] = v.y; As[kq + 2][r] = v.z; As[kq + 3][r] = v.w;
    }
#pragma unroll
    for (int i = 0; i < 4; ++i){   // B tile: coalesced rows
      int e = t + (i << 8);
      int kk = e >> 6, cc2 = e & 63;
      int col = n0 + cc2;
      Bs[kk][cc2] = (col < N) ? Bm[(size_t)(k0 + kk) * N + col] : 0.f;
    }
    __syncthreads();
#pragma unroll
    for (int kk = 0; kk < 16; ++kk){
      float4 av = *reinterpret_cast<const float4*>(&As[kk][ty << 2]);
      float4 bv = *reinterpret_cast<const float4*>(&Bs[kk][tx << 2]);
      float a4[4] = {av.x, av.y, av.z, av.w};
      float b4[4] = {bv.x, bv.y, bv.z, bv.w};
#pragma unroll
      for (int i = 0; i < 4; ++i)
#pragma unroll
        for (int j = 0; j < 4; ++j)
          acc[i][j] = fmaf(a4[i], b4[j], acc[i][j]);
    }
    __syncthreads();
  }
#pragma unroll
  for (int i = 0; i < 4; ++i){
    int r = m0 + (ty << 2) + i;
#pragma unroll
    for (int j = 0; j < 4; ++j){
      int col = n0 + (tx << 2) + j;
      if (col < N) C[(size_t)r * N + col] = acc[i][j] + (bias ? bias[col] : 0.f);
    }
  }
}

// C[M,N] = A[M,K] @ B^T where B is [N_rows, ldb] row-major (rows are the N axis).
// Optional epilogue: C *= dgelu(zscale[r*N+col]) (used for dz1 = (dz2@W2^T)*gelu'(z1)).
__global__ __launch_bounds__(256) void gemm_nt(const float* __restrict__ A, const float* __restrict__ Bm,
                                               float* __restrict__ C, int M, int N, int Kd, int ldb,
                                               const float* __restrict__ zscale){
  __shared__ __align__(16) float As[16][68];
  __shared__ __align__(16) float Bs[16][68];
  int t = threadIdx.x;
  int tx = t & 15, ty = t >> 4;
  int m0 = blockIdx.y << 6, n0 = blockIdx.x << 6;
  float acc[4][4] = {};
  for (int k0 = 0; k0 < Kd; k0 += 16){
    {
      int r = t >> 2, kq = (t & 3) << 2;
      float4 v = *reinterpret_cast<const float4*>(&A[(size_t)(m0 + r) * Kd + (k0 + kq)]);
      As[kq + 0][r] = v.x; As[kq + 1][r] = v.y; As[kq + 2][r] = v.z; As[kq + 3][r] = v.w;
    }
    {
      int col = t >> 2, kq = (t & 3) << 2;
      float4 v = make_float4(0.f, 0.f, 0.f, 0.f);
      if (n0 + col < N)
        v = *reinterpret_cast<const float4*>(&Bm[(size_t)(n0 + col) * ldb + (k0 + kq)]);
      Bs[kq + 0][col] = v.x; Bs[kq + 1][col] = v.y; Bs[kq + 2][col] = v.z; Bs[kq + 3][col] = v.w;
    }
    __syncthreads();
#pragma unroll
    for (int kk = 0; kk < 16; ++kk){
      float4 av = *reinterpret_cast<const float4*>(&As[kk][ty << 2]);
      float4 bv = *reinterpret_cast<const float4*>(&Bs[kk][tx << 2]);
      float a4[4] = {av.x, av.y, av.z, av.w};
      float b4[4] = {bv.x, bv.y, bv.z, bv.w};
#pragma unroll
      for (int i = 0; i < 4; ++i)
#pragma unroll
        for (int j = 0; j < 4; ++j)
          acc[i][j] = fmaf(a4[i], b4[j], acc[i][j]);
    }
    __syncthreads();
  }
#pragma unroll
  for (int i = 0; i < 4; ++i){
    int r = m0 + (ty << 2) + i;
#pragma unroll
    for (int j = 0; j < 4; ++j){
      int col = n0 + (tx << 2) + j;
      if (col < N){
        float v = acc[i][j];
        if (zscale) v *= dgelu_f(zscale[(size_t)r * N + col]);
        C[(size_t)r * N + col] = v;
      }
    }
  }
}

// ---------------- host ----------------
extern "C" void kernel_launch(void* const* d_in, const int* in_sizes, int n_in,
                              void* d_out, int out_size, void* d_ws, size_t ws_size,
                              hipStream_t stream){
  (void)in_sizes; (void)n_in; (void)out_size;
  const float* y_true  = (const float*)d_in[0];
  const float* cond    = (const float*)d_in[1];
  const int*   k_idx   = (const int*)d_in[2];
  const float* eps_pos = (const float*)d_in[3];
  const float* eps_neg = (const float*)d_in[4];
  const float* sel     = (const float*)d_in[5];
  const float* rv      = (const float*)d_in[6];
  const float* W1      = (const float*)d_in[7];
  const float* b1      = (const float*)d_in[8];
  const float* W2      = (const float*)d_in[9];
  const float* b2      = (const float*)d_in[10];
  const float* W3      = (const float*)d_in[11];
  const float* b3      = (const float*)d_in[12];
  const float* k_emb   = (const float*)d_in[13];

  char* w = (char*)d_ws;
  double* accs   = (double*)w; w += 256;
  float* sigma_b = (float*)w;  w += (size_t)B_TOT * 4;
  float* e_pos   = (float*)w;  w += (size_t)B_TOT * 4;
  float* e_neg   = (float*)w;  w += (size_t)B_TOT * 4;
  size_t fixed = (size_t)(w - (char*)d_ws);

  const size_t per_sample = (FEAT_DIM + 4 * HDIM + 3 * YDIM) * sizeof(float); // 37456 B
  int Mc = B_TOT;
  while (Mc > 64 && fixed + (size_t)Mc * per_sample > ws_size) Mc >>= 1;

  float* feat = (float*)w; w += (size_t)Mc * FEAT_DIM * 4;
  float* z1   = (float*)w; w += (size_t)Mc * HDIM * 4;
  float* h1   = (float*)w; w += (size_t)Mc * HDIM * 4;   // reused as dz2
  float* z2   = (float*)w; w += (size_t)Mc * HDIM * 4;
  float* dz1  = (float*)w; w += (size_t)Mc * HDIM * 4;
  float* dy   = (float*)w; w += (size_t)Mc * YDIM * 4;
  float* yhat = (float*)w; w += (size_t)Mc * YDIM * 4;
  float* yneg = (float*)w; w += (size_t)Mc * YDIM * 4;

  dim3 blk(256);
  k_zero_acc<<<1, 1, 0, stream>>>(accs);
  k_sigma<<<(B_TOT + 255) / 256, blk, 0, stream>>>(k_idx, sigma_b);

  int nCh = B_TOT / Mc;
  for (int c = 0; c < nCh; ++c){
    int b0 = c * Mc;
    int nH = Mc * HDIM;

    auto fwd = [&](const float* ysrc){
      k_feat<<<(Mc * FEAT_DIM + 255) / 256, blk, 0, stream>>>(
          ysrc, cond + (size_t)b0 * CELLS, k_emb, k_idx + b0, feat, Mc);
      gemm_nn<<<dim3(HDIM / 64, Mc / 64), blk, 0, stream>>>(feat, W1, b1, z1, Mc, HDIM, FEAT_DIM);
      k_gelu<<<(nH + 255) / 256, blk, 0, stream>>>(z1, h1, nH);
      gemm_nn<<<dim3(HDIM / 64, Mc / 64), blk, 0, stream>>>(h1, W2, b2, z2, Mc, HDIM, HDIM);
    };
    auto bwd = [&](){
      k_dz2<<<(nH + 255) / 256, blk, 0, stream>>>(z2, W3, h1, nH);
      gemm_nt<<<dim3(HDIM / 64, Mc / 64), blk, 0, stream>>>(h1, W2, dz1, Mc, HDIM, HDIM, HDIM, z1);
      gemm_nt<<<dim3((YDIM + 63) / 64, Mc / 64), blk, 0, stream>>>(dz1, W1, dy, Mc, YDIM, HDIM, HDIM, nullptr);
    };

    // ---- positive branch
    k_noise<<<(Mc * CELLS + 255) / 256, blk, 0, stream>>>(
        y_true + (size_t)b0 * YDIM, eps_pos + (size_t)b0 * YDIM, sigma_b + b0, yhat, Mc);
    fwd(yhat);
    k_energy<<<(Mc + 3) / 4, blk, 0, stream>>>(z2, W3, b3, e_pos + b0, Mc);
    bwd();
    k_mse<<<(Mc * YDIM + 255) / 256, blk, 0, stream>>>(
        dy, yhat, y_true + (size_t)b0 * YDIM, sigma_b + b0, accs, Mc);

    // ---- negative branch
    k_makeneg<<<(Mc * 64 + 255) / 256, blk, 0, stream>>>(y_true, sel, rv, yneg, b0, Mc);
    for (int r = 0; r < 5; ++r){
      fwd(yneg);
      bwd();
      k_update<<<(Mc * YDIM + 255) / 256, blk, 0, stream>>>(yneg, dy, Mc * YDIM);
    }
    k_noise<<<(Mc * CELLS + 255) / 256, blk, 0, stream>>>(
        yneg, eps_neg + (size_t)b0 * YDIM, sigma_b + b0, yhat, Mc);
    fwd(yhat);
    k_energy<<<(Mc + 3) / 4, blk, 0, stream>>>(z2, W3, b3, e_neg + b0, Mc);
  }

  k_contrast<<<(B_TOT + 255) / 256, blk, 0, stream>>>(e_pos, e_neg, accs);
  k_finalize<<<1, 1, 0, stream>>>(accs, (float*)d_out);
}

// Round 2
// 6624.504 us; speedup vs baseline: 5.1846x; 5.1846x over previous
//
#include <hip/hip_runtime.h>
#include <math.h>

#define B_TOT 16384
#define CELLS 36
#define YDIM 252       // 7*6*6
#define FEATP 448      // 416 padded to 7*64
#define FEAT_REAL 416
#define HDIM 2048
#define EMB_DIM 128
#define KSTEPS 50

typedef unsigned short ushort_t;
typedef __attribute__((ext_vector_type(8))) short short8v;
typedef __attribute__((ext_vector_type(4))) float float4v;

__device__ __forceinline__ float clip01(float x){ return fminf(fmaxf(x, 0.f), 1.f); }
__device__ __forceinline__ float gelu_f(float x){
  float u = 0.7978845608028654f * (x + 0.044715f * x * x * x);
  return 0.5f * x * (1.f + tanhf(u));
}
__device__ __forceinline__ float dgelu_f(float x){
  float x2 = x * x;
  float u = 0.7978845608028654f * (x + 0.044715f * x2 * x);
  float t = tanhf(u);
  return 0.5f * (1.f + t) + 0.5f * x * (1.f - t * t) * 0.7978845608028654f * (1.f + 0.134145f * x2);
}
__device__ __forceinline__ float clipmask(float y){ return (y == 0.f || y == 1.f) ? 0.5f : 1.f; }
__device__ __forceinline__ ushort_t f2bf(float x){
  union { float f; unsigned u; } v; v.f = x;
  unsigned r = v.u + 0x7fffu + ((v.u >> 16) & 1u);
  return (ushort_t)(r >> 16);
}
__device__ __forceinline__ float bf2f(ushort_t h){
  union { unsigned u; float f; } v; v.u = ((unsigned)h) << 16; return v.f;
}
__device__ __forceinline__ void load_lds16(const void* g, void* l){
  __builtin_amdgcn_global_load_lds((const __attribute__((address_space(1))) unsigned int*)g,
                                   (__attribute__((address_space(3))) unsigned int*)l, 16, 0, 0);
}

// ---------------- small kernels ----------------
__global__ void k_zero_acc(double* acc){ acc[0] = 0.0; acc[1] = 0.0; acc[2] = 0.0; }

__global__ void k_sigma(const int* __restrict__ k_idx, float* __restrict__ sigma_b){
  int b = blockIdx.x * blockDim.x + threadIdx.x;
  if (b >= B_TOT) return;
  int i = (KSTEPS - 1) - k_idx[b];
  float t = (float)i / (float)(KSTEPS - 1);
  float ang = (1.f - t) * 1.57079632679489662f;
  float c = cosf(ang);
  sigma_b[b] = 0.01f + 0.94f * c * c;
}

__global__ void k_cast(const float* __restrict__ in, ushort_t* __restrict__ out, int n){
  int gid = blockIdx.x * blockDim.x + threadIdx.x;
  if (gid < n) out[gid] = f2bf(in[gid]);
}
// W1T[h][f] (f padded to 448)
__global__ void k_w1t(const float* __restrict__ W1, ushort_t* __restrict__ W1T){
  int gid = blockIdx.x * blockDim.x + threadIdx.x;
  if (gid >= HDIM * FEATP) return;
  int h = gid / FEATP, f = gid - h * FEATP;
  W1T[gid] = (f < FEAT_REAL) ? f2bf(W1[(size_t)f * HDIM + h]) : (ushort_t)0;
}
// W2T[n][k] = W2[k][n]
__global__ void k_w2t(const float* __restrict__ W2, ushort_t* __restrict__ W2T){
  int gid = blockIdx.x * blockDim.x + threadIdx.x;
  if (gid >= HDIM * HDIM) return;
  int n = gid >> 11, k = gid & (HDIM - 1);
  W2T[gid] = f2bf(W2[(size_t)k * HDIM + n]);
}

__global__ void k_noise(const float* __restrict__ y, const float* __restrict__ eps,
                        const float* __restrict__ sigma_b, float* __restrict__ out, int Mc){
  int gid = blockIdx.x * blockDim.x + threadIdx.x;
  if (gid >= Mc * CELLS) return;
  int i = gid / CELLS, cell = gid - i * CELLS;
  float sigma = sigma_b[i];
  float sq = sqrtf(fmaxf(1.f - sigma * sigma, 1e-8f));
  const float* yp = y + (size_t)i * YDIM + cell;
  const float* ep = eps + (size_t)i * YDIM + cell;
  float yh[7];
#pragma unroll
  for (int ch = 0; ch < 7; ++ch){
    float e = ep[ch * CELLS] * 0.1f;
    yh[ch] = clip01(sq * yp[ch * CELLS] + sigma * e);
  }
  bool filled = yh[0] > 0.5f;
  float s = 0.f;
#pragma unroll
  for (int ch = 1; ch < 7; ++ch) s += yh[ch];
  float* op = out + (size_t)i * YDIM + cell;
  op[0] = yh[0];
#pragma unroll
  for (int ch = 1; ch < 7; ++ch){
    float v = yh[ch];
    if (filled) v = v / (s + 1e-8f);
    op[ch * CELLS] = clip01(v);
  }
}

// static part of feat: cols 252..447 (cond, emb, zero-pad) — once per chunk
__global__ void k_feat_static(const float* __restrict__ cond, const float* __restrict__ k_emb,
                              const int* __restrict__ k_idx, ushort_t* __restrict__ feat, int Mc){
  int gid = blockIdx.x * blockDim.x + threadIdx.x;
  if (gid >= Mc * 196) return;
  int i = gid / 196, c = gid - i * 196;
  float v;
  if (c < CELLS)            v = cond[(size_t)i * CELLS + c];
  else if (c < CELLS + EMB_DIM) v = k_emb[(size_t)k_idx[i] * EMB_DIM + (c - CELLS)];
  else                      v = 0.f;
  feat[(size_t)i * FEATP + YDIM + c] = f2bf(v);
}
// dynamic part: cols 0..251
__global__ void k_feat_y(const float* __restrict__ ysrc, ushort_t* __restrict__ feat, int Mc){
  int gid = blockIdx.x * blockDim.x + threadIdx.x;
  if (gid >= Mc * YDIM) return;
  int i = gid / YDIM, c = gid - i * YDIM;
  feat[(size_t)i * FEATP + c] = f2bf(clip01(ysrc[gid]));
}

__global__ void k_energy(const ushort_t* __restrict__ z2, const float* __restrict__ W3,
                         const float* __restrict__ b3, float* __restrict__ e_out, int Mc){
  int wv = (blockIdx.x * blockDim.x + threadIdx.x) >> 6;
  int lane = threadIdx.x & 63;
  if (wv >= Mc) return;
  const ushort_t* z = z2 + (size_t)wv * HDIM;
  float s = 0.f;
  for (int j = lane; j < HDIM; j += 64) s += gelu_f(bf2f(z[j])) * W3[j];
  for (int off = 32; off; off >>= 1) s += __shfl_down(s, off);
  if (lane == 0) e_out[wv] = s + b3[0];
}

__global__ void k_makeneg(const float* __restrict__ y_true, const float* __restrict__ sel,
                          const float* __restrict__ rv, float* __restrict__ y_neg,
                          int b0, int Mc){
  int w = (blockIdx.x * blockDim.x + threadIdx.x) >> 6;
  int lane = threadIdx.x & 63;
  if (w >= Mc) return;
  int b = b0 + w;
  int c = lane;
  bool active = c < CELLS;
  float yt0 = active ? y_true[(size_t)b * YDIM + c] : 0.f;
  bool filled = active && (yt0 > 0.5f);
  unsigned long long bal = __ballot(filled);
  int n_filled = __popcll(bal);
  int num_c = (int)floorf((float)n_filled * 0.3f);
  int idx = num_c - 1; if (idx < 0) idx = 0;
  float score = filled ? sel[(size_t)b * CELLS + c] : 2.0f;
  int cnt_lt = 0, cnt_le = 0;
  for (int l = 0; l < CELLS; ++l){
    float sv = __shfl(score, l);
    cnt_lt += (sv < score);
    cnt_le += (sv <= score);
  }
  float cand = (active && cnt_lt <= idx && idx < cnt_le) ? score : 3.4e38f;
  for (int off = 32; off; off >>= 1) cand = fminf(cand, __shfl_xor(cand, off));
  float thr = (num_c > 0) ? cand : -1.0f;
  bool corrupt = filled && (score <= thr);
  if (active){
    float rvv[6]; float rsum = 0.f;
#pragma unroll
    for (int ch = 0; ch < 6; ++ch){ rvv[ch] = rv[(size_t)b * (6 * CELLS) + ch * CELLS + c]; rsum += rvv[ch]; }
    y_neg[(size_t)w * YDIM + c] = corrupt ? 0.f : yt0;
#pragma unroll
    for (int ch = 0; ch < 6; ++ch){
      float val = corrupt ? rvv[ch] / rsum : y_true[(size_t)b * YDIM + (ch + 1) * CELLS + c];
      y_neg[(size_t)w * YDIM + (ch + 1) * CELLS + c] = val;
    }
  }
}

__global__ void k_mse(const float* __restrict__ dy, const float* __restrict__ yhat,
                      const float* __restrict__ y_true, const float* __restrict__ sigma_b,
                      double* __restrict__ acc, int Mc){
  int gid = blockIdx.x * blockDim.x + threadIdx.x;
  double v = 0.0;
  if (gid < Mc * YDIM){
    int i = gid / YDIM;
    float y = yhat[gid];
    float score = dy[gid] * clipmask(y);
    float sigma = sigma_b[i];
    float tgt = (y - y_true[gid]) / (sigma + 1e-8f);
    float d = score - tgt;
    v = (double)d * (double)d;
  }
  for (int off = 32; off; off >>= 1) v += __shfl_down(v, off);
  if ((threadIdx.x & 63) == 0) atomicAdd(&acc[0], v);
}

__global__ void k_contrast(const float* __restrict__ e_pos, const float* __restrict__ e_neg,
                           double* __restrict__ acc){
  int b = blockIdx.x * blockDim.x + threadIdx.x;
  double con = 0.0, reg = 0.0;
  if (b < B_TOT){
    float ep = e_pos[b], en = e_neg[b];
    float a = -ep, bb = -en;
    float m = fmaxf(a, bb);
    float lse = m + logf(expf(a - m) + expf(bb - m));
    con = (double)(ep + lse);
    reg = (double)ep + (double)en;
  }
  for (int off = 32; off; off >>= 1){ con += __shfl_down(con, off); reg += __shfl_down(reg, off); }
  if ((threadIdx.x & 63) == 0){ atomicAdd(&acc[1], con); atomicAdd(&acc[2], reg); }
}

__global__ void k_finalize(const double* __restrict__ acc, float* __restrict__ out){
  double mse = acc[0] / (double)((long long)B_TOT * YDIM);
  double con = acc[1] / (double)B_TOT;
  double reg = acc[2] / (double)B_TOT;
  out[0] = (float)(mse + con + 0.01 * reg);
}

// ---------------- MFMA GEMM: C[M,N] = A[M,K]bf16 @ BT[N,K]bf16 ----------------
// 128x128 tile, 4 waves (2x2), BK=64, 16x16x32 bf16 MFMA, global_load_lds staging.
// modes: 0: z1 path  -> outA=z1bf=bf16(v+bias), outB=h1=bf16(gelu(v+bias))
//        1: z2 path  -> v+=bias; if(outA) z2bf; if(outB) dz2=bf16(W3[col]*dgelu(v))
//        2: dz1 path -> v*=dgelu(z1bf[row*N+col]); outA=dz1 bf16
//        3: dy store -> outF[row*252+col]=v (col<N)
//        4: fused refine update on outF(=y_neg): y=clip(y+0.15*v*clipmask(y))
__global__ __launch_bounds__(256) void gemm_bt(
    const ushort_t* __restrict__ A, const ushort_t* __restrict__ BT,
    int N, int K, int mode,
    const float* __restrict__ bias, const float* __restrict__ W3,
    const ushort_t* __restrict__ z1bf,
    ushort_t* __restrict__ outA, ushort_t* __restrict__ outB,
    float* __restrict__ outF){
  __shared__ __align__(16) ushort_t Asl[128 * 64];
  __shared__ __align__(16) ushort_t Bsl[128 * 64];
  const int t = threadIdx.x, lane = t & 63, w = t >> 6;
  const int m0 = blockIdx.y << 7, n0 = blockIdx.x << 7;
  const int fr = lane & 15, kg = lane >> 4;
  const int rsub = lane >> 3;
  const int cb = (lane & 7) * 16;
  const int wr = (w >> 1) * 64, wc = (w & 1) * 64;

  float4v acc[4][4];
#pragma unroll
  for (int m = 0; m < 4; ++m)
#pragma unroll
    for (int n = 0; n < 4; ++n) acc[m][n] = (float4v)0.f;

  for (int k0 = 0; k0 < K; k0 += 64){
#pragma unroll
    for (int i = 0; i < 4; ++i){
      int c = i * 4 + w;
      int r = c * 8 + rsub;
      const char* ga = (const char*)A + ((size_t)(m0 + r) * K + k0) * 2 + cb;
      load_lds16(ga, (char*)Asl + c * 1024 + lane * 16);
      const char* gb = (const char*)BT + ((size_t)(n0 + r) * K + k0) * 2 + cb;
      load_lds16(gb, (char*)Bsl + c * 1024 + lane * 16);
    }
    __syncthreads();
#pragma unroll
    for (int kk = 0; kk < 2; ++kk){
      int kb = kk * 32 + kg * 8;
      short8v a[4], b[4];
#pragma unroll
      for (int m = 0; m < 4; ++m) a[m] = *(const short8v*)&Asl[(wr + m * 16 + fr) * 64 + kb];
#pragma unroll
      for (int n = 0; n < 4; ++n) b[n] = *(const short8v*)&Bsl[(wc + n * 16 + fr) * 64 + kb];
#pragma unroll
      for (int m = 0; m < 4; ++m)
#pragma unroll
        for (int n = 0; n < 4; ++n)
          acc[m][n] = __builtin_amdgcn_mfma_f32_16x16x32_bf16(a[m], b[n], acc[m][n], 0, 0, 0);
    }
    __syncthreads();
  }

#pragma unroll
  for (int m = 0; m < 4; ++m){
#pragma unroll
    for (int j = 0; j < 4; ++j){
      int row = m0 + wr + m * 16 + kg * 4 + j;
#pragma unroll
      for (int n = 0; n < 4; ++n){
        int col = n0 + wc + n * 16 + fr;
        float v = acc[m][n][j];
        if (mode == 0){
          v += bias[col];
          size_t o = (size_t)row * N + col;
          outA[o] = f2bf(v);
          outB[o] = f2bf(gelu_f(v));
        } else if (mode == 1){
          v += bias[col];
          size_t o = (size_t)row * N + col;
          if (outA) outA[o] = f2bf(v);
          if (outB) outB[o] = f2bf(W3[col] * dgelu_f(v));
        } else if (mode == 2){
          size_t o = (size_t)row * N + col;
          v *= dgelu_f(bf2f(z1bf[o]));
          outA[o] = f2bf(v);
        } else if (mode == 3){
          if (col < N) outF[(size_t)row * YDIM + col] = v;
        } else {
          if (col < N){
            size_t o = (size_t)row * YDIM + col;
            float y = outF[o];
            outF[o] = clip01(y + 0.15f * v * clipmask(y));
          }
        }
      }
    }
  }
}

// ---------------- host ----------------
static inline char* carve(char*& p, size_t bytes){
  char* r = p; p += (bytes + 255) & ~(size_t)255; return r;
}

extern "C" void kernel_launch(void* const* d_in, const int* in_sizes, int n_in,
                              void* d_out, int out_size, void* d_ws, size_t ws_size,
                              hipStream_t stream){
  (void)in_sizes; (void)n_in; (void)out_size;
  const float* y_true  = (const float*)d_in[0];
  const float* cond    = (const float*)d_in[1];
  const int*   k_idx   = (const int*)d_in[2];
  const float* eps_pos = (const float*)d_in[3];
  const float* eps_neg = (const float*)d_in[4];
  const float* sel     = (const float*)d_in[5];
  const float* rv      = (const float*)d_in[6];
  const float* W1      = (const float*)d_in[7];
  const float* b1      = (const float*)d_in[8];
  const float* W2      = (const float*)d_in[9];
  const float* b2      = (const float*)d_in[10];
  const float* W3      = (const float*)d_in[11];
  const float* b3      = (const float*)d_in[12];
  const float* k_emb   = (const float*)d_in[13];

  char* p = (char*)d_ws;
  double* accs   = (double*)carve(p, 3 * sizeof(double));
  float* sigma_b = (float*)carve(p, (size_t)B_TOT * 4);
  float* e_pos   = (float*)carve(p, (size_t)B_TOT * 4);
  float* e_neg   = (float*)carve(p, (size_t)B_TOT * 4);
  ushort_t* W1bf = (ushort_t*)carve(p, (size_t)FEAT_REAL * HDIM * 2);
  ushort_t* W1T  = (ushort_t*)carve(p, (size_t)HDIM * FEATP * 2);
  ushort_t* W2bf = (ushort_t*)carve(p, (size_t)HDIM * HDIM * 2);
  ushort_t* W2T  = (ushort_t*)carve(p, (size_t)HDIM * HDIM * 2);
  size_t fixed = (size_t)(p - (char*)d_ws);

  const size_t per_sample = FEATP * 2 + 5 * HDIM * 2 + 3 * YDIM * 4; // 24400
  int Mc = B_TOT;
  while (Mc > 128 && fixed + (size_t)Mc * per_sample + 65536 > ws_size) Mc >>= 1;

  ushort_t* feat = (ushort_t*)carve(p, (size_t)Mc * FEATP * 2);
  ushort_t* z1bf = (ushort_t*)carve(p, (size_t)Mc * HDIM * 2);
  ushort_t* h1   = (ushort_t*)carve(p, (size_t)Mc * HDIM * 2);
  ushort_t* z2bf = (ushort_t*)carve(p, (size_t)Mc * HDIM * 2);
  ushort_t* dz2  = (ushort_t*)carve(p, (size_t)Mc * HDIM * 2);
  ushort_t* dz1  = (ushort_t*)carve(p, (size_t)Mc * HDIM * 2);
  float* dyb  = (float*)carve(p, (size_t)Mc * YDIM * 4);
  float* yhat = (float*)carve(p, (size_t)Mc * YDIM * 4);
  float* yneg = (float*)carve(p, (size_t)Mc * YDIM * 4);

  dim3 blk(256);
  k_zero_acc<<<1, 1, 0, stream>>>(accs);
  k_sigma<<<(B_TOT + 255) / 256, blk, 0, stream>>>(k_idx, sigma_b);
  k_cast<<<(FEAT_REAL * HDIM + 255) / 256, blk, 0, stream>>>(W1, W1bf, FEAT_REAL * HDIM);
  k_w1t<<<(HDIM * FEATP + 255) / 256, blk, 0, stream>>>(W1, W1T);
  k_cast<<<(HDIM * HDIM + 255) / 256, blk, 0, stream>>>(W2, W2bf, HDIM * HDIM);
  k_w2t<<<(HDIM * HDIM + 255) / 256, blk, 0, stream>>>(W2, W2T);

  auto G = [&](const ushort_t* Ap, const ushort_t* BTp, int N, int K, int mode,
               const float* biasp, const float* W3p, const ushort_t* z1p,
               ushort_t* oA, ushort_t* oB, float* oF){
    gemm_bt<<<dim3((N + 127) / 128, Mc / 128), blk, 0, stream>>>(
        Ap, BTp, N, K, mode, biasp, W3p, z1p, oA, oB, oF);
  };

  int nCh = B_TOT / Mc;
  for (int c = 0; c < nCh; ++c){
    int b0 = c * Mc;
    k_feat_static<<<(Mc * 196 + 255) / 256, blk, 0, stream>>>(
        cond + (size_t)b0 * CELLS, k_emb, k_idx + b0, feat, Mc);

    // ---- positive branch
    k_noise<<<(Mc * CELLS + 255) / 256, blk, 0, stream>>>(
        y_true + (size_t)b0 * YDIM, eps_pos + (size_t)b0 * YDIM, sigma_b + b0, yhat, Mc);
    k_feat_y<<<(Mc * YDIM + 255) / 256, blk, 0, stream>>>(yhat, feat, Mc);
    G(feat, W1T, HDIM, FEATP, 0, b1, nullptr, nullptr, z1bf, h1, nullptr);
    G(h1, W2T, HDIM, HDIM, 1, b2, W3, nullptr, z2bf, dz2, nullptr);
    k_energy<<<(Mc + 3) / 4, blk, 0, stream>>>(z2bf, W3, b3, e_pos + b0, Mc);
    G(dz2, W2bf, HDIM, HDIM, 2, nullptr, nullptr, z1bf, dz1, nullptr, nullptr);
    G(dz1, W1bf, YDIM, HDIM, 3, nullptr, nullptr, nullptr, nullptr, nullptr, dyb);
    k_mse<<<(Mc * YDIM + 255) / 256, blk, 0, stream>>>(
        dyb, yhat, y_true + (size_t)b0 * YDIM, sigma_b + b0, accs, Mc);

    // ---- negative branch
    k_makeneg<<<(Mc * 64 + 255) / 256, blk, 0, stream>>>(y_true, sel, rv, yneg, b0, Mc);
    for (int r = 0; r < 5; ++r){
      k_feat_y<<<(Mc * YDIM + 255) / 256, blk, 0, stream>>>(yneg, feat, Mc);
      G(feat, W1T, HDIM, FEATP, 0, b1, nullptr, nullptr, z1bf, h1, nullptr);
      G(h1, W2T, HDIM, HDIM, 1, b2, W3, nullptr, nullptr, dz2, nullptr);
      G(dz2, W2bf, HDIM, HDIM, 2, nullptr, nullptr, z1bf, dz1, nullptr, nullptr);
      G(dz1, W1bf, YDIM, HDIM, 4, nullptr, nullptr, nullptr, nullptr, nullptr, yneg);
    }
    k_noise<<<(Mc * CELLS + 255) / 256, blk, 0, stream>>>(
        yneg, eps_neg + (size_t)b0 * YDIM, sigma_b + b0, yhat, Mc);
    k_feat_y<<<(Mc * YDIM + 255) / 256, blk, 0, stream>>>(yhat, feat, Mc);
    G(feat, W1T, HDIM, FEATP, 0, b1, nullptr, nullptr, z1bf, h1, nullptr);
    G(h1, W2T, HDIM, HDIM, 1, b2, W3, nullptr, z2bf, nullptr, nullptr);
    k_energy<<<(Mc + 3) / 4, blk, 0, stream>>>(z2bf, W3, b3, e_neg + b0, Mc);
  }

  k_contrast<<<(B_TOT + 255) / 256, blk, 0, stream>>>(e_pos, e_neg, accs);
  k_finalize<<<1, 1, 0, stream>>>(accs, (float*)d_out);
}

// Round 3
// 5290.137 us; speedup vs baseline: 6.4923x; 1.2522x over previous
//
#include <hip/hip_runtime.h>
#include <math.h>

#define B_TOT 16384
#define CELLS 36
#define YDIM 252       // 7*6*6
#define FEATP 448      // 416 padded to 7*64
#define FEAT_REAL 416
#define HDIM 2048
#define EMB_DIM 128
#define KSTEPS 50

typedef unsigned short ushort_t;
typedef __attribute__((ext_vector_type(8))) short short8v;
typedef __attribute__((ext_vector_type(4))) float float4v;

__device__ __forceinline__ float clip01(float x){ return fminf(fmaxf(x, 0.f), 1.f); }
__device__ __forceinline__ float gelu_f(float x){
  float u = 0.7978845608028654f * (x + 0.044715f * x * x * x);
  return 0.5f * x * (1.f + tanhf(u));
}
__device__ __forceinline__ float dgelu_f(float x){
  float x2 = x * x;
  float u = 0.7978845608028654f * (x + 0.044715f * x2 * x);
  float t = tanhf(u);
  return 0.5f * (1.f + t) + 0.5f * x * (1.f - t * t) * 0.7978845608028654f * (1.f + 0.134145f * x2);
}
__device__ __forceinline__ float clipmask(float y){ return (y == 0.f || y == 1.f) ? 0.5f : 1.f; }
__device__ __forceinline__ ushort_t f2bf(float x){
  union { float f; unsigned u; } v; v.f = x;
  unsigned r = v.u + 0x7fffu + ((v.u >> 16) & 1u);
  return (ushort_t)(r >> 16);
}
__device__ __forceinline__ float bf2f(ushort_t h){
  union { unsigned u; float f; } v; v.u = ((unsigned)h) << 16; return v.f;
}
__device__ __forceinline__ void load_lds16(const void* g, void* l){
  __builtin_amdgcn_global_load_lds((const __attribute__((address_space(1))) unsigned int*)g,
                                   (__attribute__((address_space(3))) unsigned int*)l, 16, 0, 0);
}

// ---------------- small kernels ----------------
__global__ void k_zero_acc(double* acc){ acc[0] = 0.0; acc[1] = 0.0; acc[2] = 0.0; }

__global__ void k_sigma(const int* __restrict__ k_idx, float* __restrict__ sigma_b){
  int b = blockIdx.x * blockDim.x + threadIdx.x;
  if (b >= B_TOT) return;
  int i = (KSTEPS - 1) - k_idx[b];
  float t = (float)i / (float)(KSTEPS - 1);
  float ang = (1.f - t) * 1.57079632679489662f;
  float c = cosf(ang);
  sigma_b[b] = 0.01f + 0.94f * c * c;
}

__global__ void k_cast(const float* __restrict__ in, ushort_t* __restrict__ out, int n){
  int gid = blockIdx.x * blockDim.x + threadIdx.x;
  if (gid < n) out[gid] = f2bf(in[gid]);
}
__global__ void k_w1t(const float* __restrict__ W1, ushort_t* __restrict__ W1T){
  int gid = blockIdx.x * blockDim.x + threadIdx.x;
  if (gid >= HDIM * FEATP) return;
  int h = gid / FEATP, f = gid - h * FEATP;
  W1T[gid] = (f < FEAT_REAL) ? f2bf(W1[(size_t)f * HDIM + h]) : (ushort_t)0;
}
__global__ void k_w2t(const float* __restrict__ W2, ushort_t* __restrict__ W2T){
  int gid = blockIdx.x * blockDim.x + threadIdx.x;
  if (gid >= HDIM * HDIM) return;
  int n = gid >> 11, k = gid & (HDIM - 1);
  W2T[gid] = f2bf(W2[(size_t)k * HDIM + n]);
}

// noise + direct feat write (bf16). y,eps,sigma_b chunk-offset; out/feat chunk-local.
__global__ void k_noise(const float* __restrict__ y, const float* __restrict__ eps,
                        const float* __restrict__ sigma_b, float* __restrict__ out,
                        ushort_t* __restrict__ feat, int Mc){
  int gid = blockIdx.x * blockDim.x + threadIdx.x;
  if (gid >= Mc * CELLS) return;
  int i = gid / CELLS, cell = gid - i * CELLS;
  float sigma = sigma_b[i];
  float sq = sqrtf(fmaxf(1.f - sigma * sigma, 1e-8f));
  const float* yp = y + (size_t)i * YDIM + cell;
  const float* ep = eps + (size_t)i * YDIM + cell;
  float yh[7];
#pragma unroll
  for (int ch = 0; ch < 7; ++ch){
    float e = ep[ch * CELLS] * 0.1f;
    yh[ch] = clip01(sq * yp[ch * CELLS] + sigma * e);
  }
  bool filled = yh[0] > 0.5f;
  float s = 0.f;
#pragma unroll
  for (int ch = 1; ch < 7; ++ch) s += yh[ch];
  float* op = out + (size_t)i * YDIM + cell;
  ushort_t* fp = feat + (size_t)i * FEATP + cell;
  op[0] = yh[0];
  fp[0] = f2bf(yh[0]);
#pragma unroll
  for (int ch = 1; ch < 7; ++ch){
    float v = yh[ch];
    if (filled) v = v / (s + 1e-8f);
    v = clip01(v);
    op[ch * CELLS] = v;
    fp[ch * CELLS] = f2bf(v);
  }
}

// static part of feat: cols 252..447 (cond, emb, zero-pad) — once per chunk
__global__ void k_feat_static(const float* __restrict__ cond, const float* __restrict__ k_emb,
                              const int* __restrict__ k_idx, ushort_t* __restrict__ feat, int Mc){
  int gid = blockIdx.x * blockDim.x + threadIdx.x;
  if (gid >= Mc * 196) return;
  int i = gid / 196, c = gid - i * 196;
  float v;
  if (c < CELLS)            v = cond[(size_t)i * CELLS + c];
  else if (c < CELLS + EMB_DIM) v = k_emb[(size_t)k_idx[i] * EMB_DIM + (c - CELLS)];
  else                      v = 0.f;
  feat[(size_t)i * FEATP + YDIM + c] = f2bf(v);
}

__global__ void k_energy(const ushort_t* __restrict__ z2, const float* __restrict__ W3,
                         const float* __restrict__ b3, float* __restrict__ e_out, int Mc){
  int wv = (blockIdx.x * blockDim.x + threadIdx.x) >> 6;
  int lane = threadIdx.x & 63;
  if (wv >= Mc) return;
  const ushort_t* z = z2 + (size_t)wv * HDIM;
  float s = 0.f;
  for (int j = lane; j < HDIM; j += 64) s += gelu_f(bf2f(z[j])) * W3[j];
  for (int off = 32; off; off >>= 1) s += __shfl_down(s, off);
  if (lane == 0) e_out[wv] = s + b3[0];
}

// y_neg init + feat write
__global__ void k_makeneg(const float* __restrict__ y_true, const float* __restrict__ sel,
                          const float* __restrict__ rv, float* __restrict__ y_neg,
                          ushort_t* __restrict__ feat, int b0, int Mc){
  int w = (blockIdx.x * blockDim.x + threadIdx.x) >> 6;
  int lane = threadIdx.x & 63;
  if (w >= Mc) return;
  int b = b0 + w;
  int c = lane;
  bool active = c < CELLS;
  float yt0 = active ? y_true[(size_t)b * YDIM + c] : 0.f;
  bool filled = active && (yt0 > 0.5f);
  unsigned long long bal = __ballot(filled);
  int n_filled = __popcll(bal);
  int num_c = (int)floorf((float)n_filled * 0.3f);
  int idx = num_c - 1; if (idx < 0) idx = 0;
  float score = filled ? sel[(size_t)b * CELLS + c] : 2.0f;
  int cnt_lt = 0, cnt_le = 0;
  for (int l = 0; l < CELLS; ++l){
    float sv = __shfl(score, l);
    cnt_lt += (sv < score);
    cnt_le += (sv <= score);
  }
  float cand = (active && cnt_lt <= idx && idx < cnt_le) ? score : 3.4e38f;
  for (int off = 32; off; off >>= 1) cand = fminf(cand, __shfl_xor(cand, off));
  float thr = (num_c > 0) ? cand : -1.0f;
  bool corrupt = filled && (score <= thr);
  if (active){
    float rvv[6]; float rsum = 0.f;
#pragma unroll
    for (int ch = 0; ch < 6; ++ch){ rvv[ch] = rv[(size_t)b * (6 * CELLS) + ch * CELLS + c]; rsum += rvv[ch]; }
    float v0 = corrupt ? 0.f : yt0;
    y_neg[(size_t)w * YDIM + c] = v0;
    feat[(size_t)w * FEATP + c] = f2bf(clip01(v0));
#pragma unroll
    for (int ch = 0; ch < 6; ++ch){
      float val = corrupt ? rvv[ch] / rsum : y_true[(size_t)b * YDIM + (ch + 1) * CELLS + c];
      y_neg[(size_t)w * YDIM + (ch + 1) * CELLS + c] = val;
      feat[(size_t)w * FEATP + (ch + 1) * CELLS + c] = f2bf(clip01(val));
    }
  }
}

// refine update from 4 split-K partials; also refresh feat
__global__ void k_upd(const float* __restrict__ part, float* __restrict__ yneg,
                      ushort_t* __restrict__ feat, int Mc){
  int gid = blockIdx.x * blockDim.x + threadIdx.x;
  int total = Mc * YDIM;
  if (gid >= total) return;
  int i = gid / YDIM, c = gid - i * YDIM;
  float g = ((part[gid] + part[(size_t)total + gid]) +
             (part[2 * (size_t)total + gid] + part[3 * (size_t)total + gid]));
  float y = yneg[gid];
  y = clip01(y + 0.15f * g * clipmask(y));
  yneg[gid] = y;
  feat[(size_t)i * FEATP + c] = f2bf(y);
}

// mse: grid-stride, block-reduce, 1 atomic per block
__global__ __launch_bounds__(256) void k_mse(const float* __restrict__ part, const float* __restrict__ yhat,
                      const float* __restrict__ y_true, const float* __restrict__ sigma_b,
                      double* __restrict__ acc, int Mc){
  int total = Mc * YDIM;
  double v = 0.0;
  for (int gid = blockIdx.x * blockDim.x + threadIdx.x; gid < total; gid += gridDim.x * blockDim.x){
    int i = gid / YDIM;
    float y = yhat[gid];
    float dy = ((part[gid] + part[(size_t)total + gid]) +
                (part[2 * (size_t)total + gid] + part[3 * (size_t)total + gid]));
    float score = dy * clipmask(y);
    float sigma = sigma_b[i];
    float tgt = (y - y_true[gid]) / (sigma + 1e-8f);
    float d = score - tgt;
    v += (double)d * (double)d;
  }
  for (int off = 32; off; off >>= 1) v += __shfl_down(v, off);
  __shared__ double wsum[4];
  int lane = threadIdx.x & 63, wid = threadIdx.x >> 6;
  if (lane == 0) wsum[wid] = v;
  __syncthreads();
  if (threadIdx.x == 0) atomicAdd(&acc[0], (wsum[0] + wsum[1]) + (wsum[2] + wsum[3]));
}

__global__ __launch_bounds__(256) void k_contrast(const float* __restrict__ e_pos, const float* __restrict__ e_neg,
                           double* __restrict__ acc){
  double con = 0.0, reg = 0.0;
  for (int b = blockIdx.x * blockDim.x + threadIdx.x; b < B_TOT; b += gridDim.x * blockDim.x){
    float ep = e_pos[b], en = e_neg[b];
    float a = -ep, bb = -en;
    float m = fmaxf(a, bb);
    float lse = m + logf(expf(a - m) + expf(bb - m));
    con += (double)(ep + lse);
    reg += (double)ep + (double)en;
  }
  for (int off = 32; off; off >>= 1){ con += __shfl_down(con, off); reg += __shfl_down(reg, off); }
  __shared__ double wc[4], wr[4];
  int lane = threadIdx.x & 63, wid = threadIdx.x >> 6;
  if (lane == 0){ wc[wid] = con; wr[wid] = reg; }
  __syncthreads();
  if (threadIdx.x == 0){
    atomicAdd(&acc[1], (wc[0] + wc[1]) + (wc[2] + wc[3]));
    atomicAdd(&acc[2], (wr[0] + wr[1]) + (wr[2] + wr[3]));
  }
}

__global__ void k_finalize(const double* __restrict__ acc, float* __restrict__ out){
  double mse = acc[0] / (double)((long long)B_TOT * YDIM);
  double con = acc[1] / (double)B_TOT;
  double reg = acc[2] / (double)B_TOT;
  out[0] = (float)(mse + con + 0.01 * reg);
}

// ---------------- MFMA GEMM: C[M,N] = A[M,K]bf16 @ BT[N,K]bf16 ----------------
// 128x128 tile, 4 waves (2x2), BK=64, 16x16x32 bf16 MFMA, global_load_lds staging.
// modes: 0: z1 path  -> outA=z1bf=bf16(v+bias), outB=h1=bf16(gelu(v+bias))
//        1: z2 path  -> v+=bias; if(outA) z2bf; if(outB) dz2=bf16(W3[col]*dgelu(v))
//        2: dz1 path -> v*=dgelu(z1bf[row*N+col]); outA=dz1 bf16
__global__ __launch_bounds__(256) void gemm_bt(
    const ushort_t* __restrict__ A, const ushort_t* __restrict__ BT,
    int N, int K, int mode,
    const float* __restrict__ bias, const float* __restrict__ W3,
    const ushort_t* __restrict__ z1bf,
    ushort_t* __restrict__ outA, ushort_t* __restrict__ outB){
  __shared__ __align__(16) ushort_t Asl[128 * 64];
  __shared__ __align__(16) ushort_t Bsl[128 * 64];
  const int t = threadIdx.x, lane = t & 63, w = t >> 6;
  const int m0 = blockIdx.y << 7, n0 = blockIdx.x << 7;
  const int fr = lane & 15, kg = lane >> 4;
  const int rsub = lane >> 3;
  const int cb = (lane & 7) * 16;
  const int wr = (w >> 1) * 64, wc = (w & 1) * 64;

  float4v acc[4][4];
#pragma unroll
  for (int m = 0; m < 4; ++m)
#pragma unroll
    for (int n = 0; n < 4; ++n) acc[m][n] = (float4v)0.f;

  for (int k0 = 0; k0 < K; k0 += 64){
#pragma unroll
    for (int i = 0; i < 4; ++i){
      int c = i * 4 + w;
      int r = c * 8 + rsub;
      const char* ga = (const char*)A + ((size_t)(m0 + r) * K + k0) * 2 + cb;
      load_lds16(ga, (char*)Asl + c * 1024 + lane * 16);
      const char* gb = (const char*)BT + ((size_t)(n0 + r) * K + k0) * 2 + cb;
      load_lds16(gb, (char*)Bsl + c * 1024 + lane * 16);
    }
    __syncthreads();
#pragma unroll
    for (int kk = 0; kk < 2; ++kk){
      int kb = kk * 32 + kg * 8;
      short8v a[4], b[4];
#pragma unroll
      for (int m = 0; m < 4; ++m) a[m] = *(const short8v*)&Asl[(wr + m * 16 + fr) * 64 + kb];
#pragma unroll
      for (int n = 0; n < 4; ++n) b[n] = *(const short8v*)&Bsl[(wc + n * 16 + fr) * 64 + kb];
#pragma unroll
      for (int m = 0; m < 4; ++m)
#pragma unroll
        for (int n = 0; n < 4; ++n)
          acc[m][n] = __builtin_amdgcn_mfma_f32_16x16x32_bf16(a[m], b[n], acc[m][n], 0, 0, 0);
    }
    __syncthreads();
  }

#pragma unroll
  for (int m = 0; m < 4; ++m){
#pragma unroll
    for (int j = 0; j < 4; ++j){
      int row = m0 + wr + m * 16 + kg * 4 + j;
#pragma unroll
      for (int n = 0; n < 4; ++n){
        int col = n0 + wc + n * 16 + fr;
        float v = acc[m][n][j];
        size_t o = (size_t)row * N + col;
        if (mode == 0){
          v += bias[col];
          outA[o] = f2bf(v);
          outB[o] = f2bf(gelu_f(v));
        } else if (mode == 1){
          v += bias[col];
          if (outA) outA[o] = f2bf(v);
          if (outB) outB[o] = f2bf(W3[col] * dgelu_f(v));
        } else {
          v *= dgelu_f(bf2f(z1bf[o]));
          outA[o] = f2bf(v);
        }
      }
    }
  }
}

// split-K dy GEMM: part[ks][m][col<252] = dz1[m, ks*512:(ks+1)*512] @ W1bf[col, same]^T
// grid: (2, Mc/128, 4)
__global__ __launch_bounds__(256) void gemm_dy(
    const ushort_t* __restrict__ A, const ushort_t* __restrict__ BT,
    float* __restrict__ part, int Mc){
  __shared__ __align__(16) ushort_t Asl[128 * 64];
  __shared__ __align__(16) ushort_t Bsl[128 * 64];
  const int t = threadIdx.x, lane = t & 63, w = t >> 6;
  const int m0 = blockIdx.y << 7, n0 = blockIdx.x << 7;
  const int ks = blockIdx.z;
  const int kbeg = ks * (HDIM / 4), kend = kbeg + (HDIM / 4);
  const int fr = lane & 15, kg = lane >> 4;
  const int rsub = lane >> 3;
  const int cb = (lane & 7) * 16;
  const int wr = (w >> 1) * 64, wc = (w & 1) * 64;

  float4v acc[4][4];
#pragma unroll
  for (int m = 0; m < 4; ++m)
#pragma unroll
    for (int n = 0; n < 4; ++n) acc[m][n] = (float4v)0.f;

  for (int k0 = kbeg; k0 < kend; k0 += 64){
#pragma unroll
    for (int i = 0; i < 4; ++i){
      int c = i * 4 + w;
      int r = c * 8 + rsub;
      const char* ga = (const char*)A + ((size_t)(m0 + r) * HDIM + k0) * 2 + cb;
      load_lds16(ga, (char*)Asl + c * 1024 + lane * 16);
      const char* gb = (const char*)BT + ((size_t)(n0 + r) * HDIM + k0) * 2 + cb;
      load_lds16(gb, (char*)Bsl + c * 1024 + lane * 16);
    }
    __syncthreads();
#pragma unroll
    for (int kk = 0; kk < 2; ++kk){
      int kb = kk * 32 + kg * 8;
      short8v a[4], b[4];
#pragma unroll
      for (int m = 0; m < 4; ++m) a[m] = *(const short8v*)&Asl[(wr + m * 16 + fr) * 64 + kb];
#pragma unroll
      for (int n = 0; n < 4; ++n) b[n] = *(const short8v*)&Bsl[(wc + n * 16 + fr) * 64 + kb];
#pragma unroll
      for (int m = 0; m < 4; ++m)
#pragma unroll
        for (int n = 0; n < 4; ++n)
          acc[m][n] = __builtin_amdgcn_mfma_f32_16x16x32_bf16(a[m], b[n], acc[m][n], 0, 0, 0);
    }
    __syncthreads();
  }

  float* pp = part + (size_t)ks * Mc * YDIM;
#pragma unroll
  for (int m = 0; m < 4; ++m){
#pragma unroll
    for (int j = 0; j < 4; ++j){
      int row = m0 + wr + m * 16 + kg * 4 + j;
#pragma unroll
      for (int n = 0; n < 4; ++n){
        int col = n0 + wc + n * 16 + fr;
        if (col < YDIM) pp[(size_t)row * YDIM + col] = acc[m][n][j];
      }
    }
  }
}

// ---------------- host ----------------
static inline char* carve(char*& p, size_t bytes){
  char* r = p; p += (bytes + 255) & ~(size_t)255; return r;
}

extern "C" void kernel_launch(void* const* d_in, const int* in_sizes, int n_in,
                              void* d_out, int out_size, void* d_ws, size_t ws_size,
                              hipStream_t stream){
  (void)in_sizes; (void)n_in; (void)out_size;
  const float* y_true  = (const float*)d_in[0];
  const float* cond    = (const float*)d_in[1];
  const int*   k_idx   = (const int*)d_in[2];
  const float* eps_pos = (const float*)d_in[3];
  const float* eps_neg = (const float*)d_in[4];
  const float* sel     = (const float*)d_in[5];
  const float* rv      = (const float*)d_in[6];
  const float* W1      = (const float*)d_in[7];
  const float* b1      = (const float*)d_in[8];
  const float* W2      = (const float*)d_in[9];
  const float* b2      = (const float*)d_in[10];
  const float* W3      = (const float*)d_in[11];
  const float* b3      = (const float*)d_in[12];
  const float* k_emb   = (const float*)d_in[13];

  char* p = (char*)d_ws;
  double* accs   = (double*)carve(p, 3 * sizeof(double));
  float* sigma_b = (float*)carve(p, (size_t)B_TOT * 4);
  float* e_pos   = (float*)carve(p, (size_t)B_TOT * 4);
  float* e_neg   = (float*)carve(p, (size_t)B_TOT * 4);
  ushort_t* W1bf = (ushort_t*)carve(p, (size_t)FEAT_REAL * HDIM * 2);
  ushort_t* W1T  = (ushort_t*)carve(p, (size_t)HDIM * FEATP * 2);
  ushort_t* W2bf = (ushort_t*)carve(p, (size_t)HDIM * HDIM * 2);
  ushort_t* W2T  = (ushort_t*)carve(p, (size_t)HDIM * HDIM * 2);
  size_t fixed = (size_t)(p - (char*)d_ws);

  // per-sample: feat(448*2) + 5 bf16 H-planes (z1bf,h1,z2bf,dz2,dz1) + yhat,yneg f32
  // dy partials (4 x 252 f32 = 4032B) alias the dead h1 plane (4096B) during bwd.
  const size_t per_sample = FEATP * 2 + 5 * HDIM * 2 + 2 * YDIM * 4; // 23392
  int Mc = B_TOT;
  while (Mc > 128 && fixed + (size_t)Mc * per_sample + 65536 > ws_size) Mc >>= 1;

  ushort_t* feat = (ushort_t*)carve(p, (size_t)Mc * FEATP * 2);
  ushort_t* z1bf = (ushort_t*)carve(p, (size_t)Mc * HDIM * 2);
  ushort_t* h1   = (ushort_t*)carve(p, (size_t)Mc * HDIM * 2);
  ushort_t* z2bf = (ushort_t*)carve(p, (size_t)Mc * HDIM * 2);
  ushort_t* dz2  = (ushort_t*)carve(p, (size_t)Mc * HDIM * 2);
  ushort_t* dz1  = (ushort_t*)carve(p, (size_t)Mc * HDIM * 2);
  float* yhat = (float*)carve(p, (size_t)Mc * YDIM * 4);
  float* yneg = (float*)carve(p, (size_t)Mc * YDIM * 4);
  float* part = (float*)h1;  // h1 is dead once the z2 GEMM has consumed it

  dim3 blk(256);
  k_zero_acc<<<1, 1, 0, stream>>>(accs);
  k_sigma<<<(B_TOT + 255) / 256, blk, 0, stream>>>(k_idx, sigma_b);
  k_cast<<<(FEAT_REAL * HDIM + 255) / 256, blk, 0, stream>>>(W1, W1bf, FEAT_REAL * HDIM);
  k_w1t<<<(HDIM * FEATP + 255) / 256, blk, 0, stream>>>(W1, W1T);
  k_cast<<<(HDIM * HDIM + 255) / 256, blk, 0, stream>>>(W2, W2bf, HDIM * HDIM);
  k_w2t<<<(HDIM * HDIM + 255) / 256, blk, 0, stream>>>(W2, W2T);

  auto G = [&](const ushort_t* Ap, const ushort_t* BTp, int N, int K, int mode,
               const float* biasp, const float* W3p, const ushort_t* z1p,
               ushort_t* oA, ushort_t* oB){
    gemm_bt<<<dim3(N / 128, Mc / 128), blk, 0, stream>>>(
        Ap, BTp, N, K, mode, biasp, W3p, z1p, oA, oB);
  };
  auto Gdy = [&](){
    gemm_dy<<<dim3(2, Mc / 128, 4), blk, 0, stream>>>(dz1, W1bf, part, Mc);
  };

  int nCh = B_TOT / Mc;
  for (int c = 0; c < nCh; ++c){
    int b0 = c * Mc;
    k_feat_static<<<(Mc * 196 + 255) / 256, blk, 0, stream>>>(
        cond + (size_t)b0 * CELLS, k_emb, k_idx + b0, feat, Mc);

    // ---- positive branch
    k_noise<<<(Mc * CELLS + 255) / 256, blk, 0, stream>>>(
        y_true + (size_t)b0 * YDIM, eps_pos + (size_t)b0 * YDIM, sigma_b + b0, yhat, feat, Mc);
    G(feat, W1T, HDIM, FEATP, 0, b1, nullptr, nullptr, z1bf, h1);
    G(h1, W2T, HDIM, HDIM, 1, b2, W3, nullptr, z2bf, dz2);
    k_energy<<<(Mc + 3) / 4, blk, 0, stream>>>(z2bf, W3, b3, e_pos + b0, Mc);
    G(dz2, W2bf, HDIM, HDIM, 2, nullptr, nullptr, z1bf, dz1, nullptr);
    Gdy();
    k_mse<<<512, blk, 0, stream>>>(part, yhat, y_true + (size_t)b0 * YDIM, sigma_b + b0, accs, Mc);

    // ---- negative branch
    k_makeneg<<<(Mc * 64 + 255) / 256, blk, 0, stream>>>(y_true, sel, rv, yneg, feat, b0, Mc);
    for (int r = 0; r < 5; ++r){
      G(feat, W1T, HDIM, FEATP, 0, b1, nullptr, nullptr, z1bf, h1);
      G(h1, W2T, HDIM, HDIM, 1, b2, W3, nullptr, nullptr, dz2);
      G(dz2, W2bf, HDIM, HDIM, 2, nullptr, nullptr, z1bf, dz1, nullptr);
      Gdy();
      k_upd<<<(Mc * YDIM + 255) / 256, blk, 0, stream>>>(part, yneg, feat, Mc);
    }
    k_noise<<<(Mc * CELLS + 255) / 256, blk, 0, stream>>>(
        yneg, eps_neg + (size_t)b0 * YDIM, sigma_b + b0, yhat, feat, Mc);
    G(feat, W1T, HDIM, FEATP, 0, b1, nullptr, nullptr, z1bf, h1);
    G(h1, W2T, HDIM, HDIM, 1, b2, W3, nullptr, z2bf, nullptr);
    k_energy<<<(Mc + 3) / 4, blk, 0, stream>>>(z2bf, W3, b3, e_neg + b0, Mc);
  }

  k_contrast<<<64, blk, 0, stream>>>(e_pos, e_neg, accs);
  k_finalize<<<1, 1, 0, stream>>>(accs, (float*)d_out);
}

// Round 4
// 5038.925 us; speedup vs baseline: 6.8160x; 1.0499x over previous
//
#include <hip/hip_runtime.h>
#include <math.h>

#define B_TOT 16384
#define CELLS 36
#define YDIM 252       // 7*6*6
#define FEATP 448      // 416 padded to 7*64
#define FEAT_REAL 416
#define HDIM 2048
#define EMB_DIM 128
#define KSTEPS 50

typedef unsigned short ushort_t;
typedef __attribute__((ext_vector_type(8))) short short8v;
typedef __attribute__((ext_vector_type(4))) float float4v;

__device__ __forceinline__ float clip01(float x){ return fminf(fmaxf(x, 0.f), 1.f); }
// fast tanh via v_exp_f32: t = 1 - 2/(e^{2u}+1); exact at +-inf, err ~1e-6 rel.
__device__ __forceinline__ float tanh_fast(float u){
  float e = __expf(2.f * u);
  return 1.f - 2.f / (e + 1.f);
}
__device__ __forceinline__ float gelu_f(float x){
  float u = 0.7978845608028654f * (x + 0.044715f * x * x * x);
  return 0.5f * x * (1.f + tanh_fast(u));
}
__device__ __forceinline__ float dgelu_f(float x){
  float x2 = x * x;
  float u = 0.7978845608028654f * (x + 0.044715f * x2 * x);
  float t = tanh_fast(u);
  return 0.5f * (1.f + t) + 0.5f * x * (1.f - t * t) * 0.7978845608028654f * (1.f + 0.134145f * x2);
}
__device__ __forceinline__ float clipmask(float y){ return (y == 0.f || y == 1.f) ? 0.5f : 1.f; }
__device__ __forceinline__ ushort_t f2bf(float x){
  union { float f; unsigned u; } v; v.f = x;
  unsigned r = v.u + 0x7fffu + ((v.u >> 16) & 1u);
  return (ushort_t)(r >> 16);
}
__device__ __forceinline__ float bf2f(ushort_t h){
  union { unsigned u; float f; } v; v.u = ((unsigned)h) << 16; return v.f;
}
__device__ __forceinline__ void load_lds16(const void* g, void* l){
  __builtin_amdgcn_global_load_lds((const __attribute__((address_space(1))) unsigned int*)g,
                                   (__attribute__((address_space(3))) unsigned int*)l, 16, 0, 0);
}
// m204 bijective XCD swizzle: consecutive remapped ids within an XCD share `by`
// (A row-panel stays L2-resident; weight panel streams once per XCD).
__device__ __forceinline__ void xcd_swizzle(int GX, int GY, int& bx, int& by){
  int nwg = GX * GY;
  int orig = by * GX + bx;
  int q = nwg >> 3, r = nwg & 7;
  int xcd = orig & 7, loc = orig >> 3;
  int lin = (xcd < r ? xcd * (q + 1) : r * (q + 1) + (xcd - r) * q) + loc;
  bx = lin % GX; by = lin / GX;
}

// ---------------- small kernels ----------------
__global__ void k_zero_acc(double* acc){ acc[0] = 0.0; acc[1] = 0.0; acc[2] = 0.0; }

__global__ void k_sigma(const int* __restrict__ k_idx, float* __restrict__ sigma_b){
  int b = blockIdx.x * blockDim.x + threadIdx.x;
  if (b >= B_TOT) return;
  int i = (KSTEPS - 1) - k_idx[b];
  float t = (float)i / (float)(KSTEPS - 1);
  float ang = (1.f - t) * 1.57079632679489662f;
  float c = cosf(ang);
  sigma_b[b] = 0.01f + 0.94f * c * c;
}

__global__ void k_cast(const float* __restrict__ in, ushort_t* __restrict__ out, int n){
  int gid = blockIdx.x * blockDim.x + threadIdx.x;
  if (gid < n) out[gid] = f2bf(in[gid]);
}
__global__ void k_w1t(const float* __restrict__ W1, ushort_t* __restrict__ W1T){
  int gid = blockIdx.x * blockDim.x + threadIdx.x;
  if (gid >= HDIM * FEATP) return;
  int h = gid / FEATP, f = gid - h * FEATP;
  W1T[gid] = (f < FEAT_REAL) ? f2bf(W1[(size_t)f * HDIM + h]) : (ushort_t)0;
}
__global__ void k_w2t(const float* __restrict__ W2, ushort_t* __restrict__ W2T){
  int gid = blockIdx.x * blockDim.x + threadIdx.x;
  if (gid >= HDIM * HDIM) return;
  int n = gid >> 11, k = gid & (HDIM - 1);
  W2T[gid] = f2bf(W2[(size_t)k * HDIM + n]);
}

// noise + direct feat write (bf16). y,eps,sigma_b chunk-offset; out/feat chunk-local.
__global__ void k_noise(const float* __restrict__ y, const float* __restrict__ eps,
                        const float* __restrict__ sigma_b, float* __restrict__ out,
                        ushort_t* __restrict__ feat, int Mc){
  int gid = blockIdx.x * blockDim.x + threadIdx.x;
  if (gid >= Mc * CELLS) return;
  int i = gid / CELLS, cell = gid - i * CELLS;
  float sigma = sigma_b[i];
  float sq = sqrtf(fmaxf(1.f - sigma * sigma, 1e-8f));
  const float* yp = y + (size_t)i * YDIM + cell;
  const float* ep = eps + (size_t)i * YDIM + cell;
  float yh[7];
#pragma unroll
  for (int ch = 0; ch < 7; ++ch){
    float e = ep[ch * CELLS] * 0.1f;
    yh[ch] = clip01(sq * yp[ch * CELLS] + sigma * e);
  }
  bool filled = yh[0] > 0.5f;
  float s = 0.f;
#pragma unroll
  for (int ch = 1; ch < 7; ++ch) s += yh[ch];
  float* op = out + (size_t)i * YDIM + cell;
  ushort_t* fp = feat + (size_t)i * FEATP + cell;
  op[0] = yh[0];
  fp[0] = f2bf(yh[0]);
#pragma unroll
  for (int ch = 1; ch < 7; ++ch){
    float v = yh[ch];
    if (filled) v = v / (s + 1e-8f);
    v = clip01(v);
    op[ch * CELLS] = v;
    fp[ch * CELLS] = f2bf(v);
  }
}

// static part of feat: cols 252..447 (cond, emb, zero-pad) — once per chunk
__global__ void k_feat_static(const float* __restrict__ cond, const float* __restrict__ k_emb,
                              const int* __restrict__ k_idx, ushort_t* __restrict__ feat, int Mc){
  int gid = blockIdx.x * blockDim.x + threadIdx.x;
  if (gid >= Mc * 196) return;
  int i = gid / 196, c = gid - i * 196;
  float v;
  if (c < CELLS)            v = cond[(size_t)i * CELLS + c];
  else if (c < CELLS + EMB_DIM) v = k_emb[(size_t)k_idx[i] * EMB_DIM + (c - CELLS)];
  else                      v = 0.f;
  feat[(size_t)i * FEATP + YDIM + c] = f2bf(v);
}

// vectorized energy: wave per row, short8 bf16 loads
__global__ void k_energy(const ushort_t* __restrict__ z2, const float* __restrict__ W3,
                         const float* __restrict__ b3, float* __restrict__ e_out, int Mc){
  int wv = (blockIdx.x * blockDim.x + threadIdx.x) >> 6;
  int lane = threadIdx.x & 63;
  if (wv >= Mc) return;
  const ushort_t* z = z2 + (size_t)wv * HDIM;
  float s = 0.f;
#pragma unroll
  for (int base = 0; base < HDIM; base += 512){
    int j = base + lane * 8;
    short8v zv = *(const short8v*)&z[j];
    float4 w0 = *(const float4*)&W3[j];
    float4 w1 = *(const float4*)&W3[j + 4];
    s += gelu_f(bf2f((ushort_t)zv[0])) * w0.x + gelu_f(bf2f((ushort_t)zv[1])) * w0.y +
         gelu_f(bf2f((ushort_t)zv[2])) * w0.z + gelu_f(bf2f((ushort_t)zv[3])) * w0.w +
         gelu_f(bf2f((ushort_t)zv[4])) * w1.x + gelu_f(bf2f((ushort_t)zv[5])) * w1.y +
         gelu_f(bf2f((ushort_t)zv[6])) * w1.z + gelu_f(bf2f((ushort_t)zv[7])) * w1.w;
  }
  for (int off = 32; off; off >>= 1) s += __shfl_down(s, off);
  if (lane == 0) e_out[wv] = s + b3[0];
}

// y_neg init + feat write
__global__ void k_makeneg(const float* __restrict__ y_true, const float* __restrict__ sel,
                          const float* __restrict__ rv, float* __restrict__ y_neg,
                          ushort_t* __restrict__ feat, int b0, int Mc){
  int w = (blockIdx.x * blockDim.x + threadIdx.x) >> 6;
  int lane = threadIdx.x & 63;
  if (w >= Mc) return;
  int b = b0 + w;
  int c = lane;
  bool active = c < CELLS;
  float yt0 = active ? y_true[(size_t)b * YDIM + c] : 0.f;
  bool filled = active && (yt0 > 0.5f);
  unsigned long long bal = __ballot(filled);
  int n_filled = __popcll(bal);
  int num_c = (int)floorf((float)n_filled * 0.3f);
  int idx = num_c - 1; if (idx < 0) idx = 0;
  float score = filled ? sel[(size_t)b * CELLS + c] : 2.0f;
  int cnt_lt = 0, cnt_le = 0;
  for (int l = 0; l < CELLS; ++l){
    float sv = __shfl(score, l);
    cnt_lt += (sv < score);
    cnt_le += (sv <= score);
  }
  float cand = (active && cnt_lt <= idx && idx < cnt_le) ? score : 3.4e38f;
  for (int off = 32; off; off >>= 1) cand = fminf(cand, __shfl_xor(cand, off));
  float thr = (num_c > 0) ? cand : -1.0f;
  bool corrupt = filled && (score <= thr);
  if (active){
    float rvv[6]; float rsum = 0.f;
#pragma unroll
    for (int ch = 0; ch < 6; ++ch){ rvv[ch] = rv[(size_t)b * (6 * CELLS) + ch * CELLS + c]; rsum += rvv[ch]; }
    float v0 = corrupt ? 0.f : yt0;
    y_neg[(size_t)w * YDIM + c] = v0;
    feat[(size_t)w * FEATP + c] = f2bf(clip01(v0));
#pragma unroll
    for (int ch = 0; ch < 6; ++ch){
      float val = corrupt ? rvv[ch] / rsum : y_true[(size_t)b * YDIM + (ch + 1) * CELLS + c];
      y_neg[(size_t)w * YDIM + (ch + 1) * CELLS + c] = val;
      feat[(size_t)w * FEATP + (ch + 1) * CELLS + c] = f2bf(clip01(val));
    }
  }
}

// refine update from 4 split-K partials; also refresh feat
__global__ void k_upd(const float* __restrict__ part, float* __restrict__ yneg,
                      ushort_t* __restrict__ feat, int Mc){
  int gid = blockIdx.x * blockDim.x + threadIdx.x;
  int total = Mc * YDIM;
  if (gid >= total) return;
  int i = gid / YDIM, c = gid - i * YDIM;
  float g = ((part[gid] + part[(size_t)total + gid]) +
             (part[2 * (size_t)total + gid] + part[3 * (size_t)total + gid]));
  float y = yneg[gid];
  y = clip01(y + 0.15f * g * clipmask(y));
  yneg[gid] = y;
  feat[(size_t)i * FEATP + c] = f2bf(y);
}

// mse: grid-stride, block-reduce, 1 atomic per block
__global__ __launch_bounds__(256) void k_mse(const float* __restrict__ part, const float* __restrict__ yhat,
                      const float* __restrict__ y_true, const float* __restrict__ sigma_b,
                      double* __restrict__ acc, int Mc){
  int total = Mc * YDIM;
  double v = 0.0;
  for (int gid = blockIdx.x * blockDim.x + threadIdx.x; gid < total; gid += gridDim.x * blockDim.x){
    int i = gid / YDIM;
    float y = yhat[gid];
    float dy = ((part[gid] + part[(size_t)total + gid]) +
                (part[2 * (size_t)total + gid] + part[3 * (size_t)total + gid]));
    float score = dy * clipmask(y);
    float sigma = sigma_b[i];
    float tgt = (y - y_true[gid]) / (sigma + 1e-8f);
    float d = score - tgt;
    v += (double)d * (double)d;
  }
  for (int off = 32; off; off >>= 1) v += __shfl_down(v, off);
  __shared__ double wsum[4];
  int lane = threadIdx.x & 63, wid = threadIdx.x >> 6;
  if (lane == 0) wsum[wid] = v;
  __syncthreads();
  if (threadIdx.x == 0) atomicAdd(&acc[0], (wsum[0] + wsum[1]) + (wsum[2] + wsum[3]));
}

__global__ __launch_bounds__(256) void k_contrast(const float* __restrict__ e_pos, const float* __restrict__ e_neg,
                           double* __restrict__ acc){
  double con = 0.0, reg = 0.0;
  for (int b = blockIdx.x * blockDim.x + threadIdx.x; b < B_TOT; b += gridDim.x * blockDim.x){
    float ep = e_pos[b], en = e_neg[b];
    float a = -ep, bb = -en;
    float m = fmaxf(a, bb);
    float lse = m + logf(expf(a - m) + expf(bb - m));
    con += (double)(ep + lse);
    reg += (double)ep + (double)en;
  }
  for (int off = 32; off; off >>= 1){ con += __shfl_down(con, off); reg += __shfl_down(reg, off); }
  __shared__ double wc[4], wr[4];
  int lane = threadIdx.x & 63, wid = threadIdx.x >> 6;
  if (lane == 0){ wc[wid] = con; wr[wid] = reg; }
  __syncthreads();
  if (threadIdx.x == 0){
    atomicAdd(&acc[1], (wc[0] + wc[1]) + (wc[2] + wc[3]));
    atomicAdd(&acc[2], (wr[0] + wr[1]) + (wr[2] + wr[3]));
  }
}

__global__ void k_finalize(const double* __restrict__ acc, float* __restrict__ out){
  double mse = acc[0] / (double)((long long)B_TOT * YDIM);
  double con = acc[1] / (double)B_TOT;
  double reg = acc[2] / (double)B_TOT;
  out[0] = (float)(mse + con + 0.01 * reg);
}

// staging macro: wave-uniform LDS base + lane*16 (HW pattern for global_load_lds)
#define STAGE(Asl_, Bsl_, k0_) do { \
  _Pragma("unroll") \
  for (int i_ = 0; i_ < 4; ++i_){ \
    int c_ = i_ * 4 + w; \
    int r_ = c_ * 8 + rsub; \
    load_lds16((const char*)A + ((size_t)(m0 + r_) * K + (k0_)) * 2 + cb, (char*)(Asl_) + c_ * 1024 + lane * 16); \
    load_lds16((const char*)BT + ((size_t)(n0 + r_) * K + (k0_)) * 2 + cb, (char*)(Bsl_) + c_ * 1024 + lane * 16); \
  } } while (0)

#define MFMA_TILE(Asl_, Bsl_) do { \
  _Pragma("unroll") \
  for (int kk = 0; kk < 2; ++kk){ \
    int kb = kk * 32 + kg * 8; \
    short8v a[4], b[4]; \
    _Pragma("unroll") \
    for (int m = 0; m < 4; ++m) a[m] = *(const short8v*)&(Asl_)[(wr + m * 16 + fr) * 64 + kb]; \
    _Pragma("unroll") \
    for (int n = 0; n < 4; ++n) b[n] = *(const short8v*)&(Bsl_)[(wc + n * 16 + fr) * 64 + kb]; \
    _Pragma("unroll") \
    for (int m = 0; m < 4; ++m) \
      _Pragma("unroll") \
      for (int n = 0; n < 4; ++n) \
        acc[m][n] = __builtin_amdgcn_mfma_f32_16x16x32_bf16(a[m], b[n], acc[m][n], 0, 0, 0); \
  } } while (0)

// ---------------- MFMA GEMM: C[M,N] = A[M,K]bf16 @ BT[N,K]bf16 ----------------
// 128x128 tile, 4 waves, BK=64, double-buffered LDS, STAGE-next-then-compute
// (one __syncthreads per K-tile; its vmcnt(0) drain lands after compute).
__global__ __launch_bounds__(256) void gemm_bt(
    const ushort_t* __restrict__ A, const ushort_t* __restrict__ BT,
    int N, int K, int mode,
    const float* __restrict__ bias, const float* __restrict__ W3,
    const ushort_t* __restrict__ z1bf,
    ushort_t* __restrict__ outA, ushort_t* __restrict__ outB){
  __shared__ __align__(16) ushort_t Asl[2][128 * 64];
  __shared__ __align__(16) ushort_t Bsl[2][128 * 64];
  const int t = threadIdx.x, lane = t & 63, w = t >> 6;
  int bx = blockIdx.x, by = blockIdx.y;
  xcd_swizzle(gridDim.x, gridDim.y, bx, by);
  const int m0 = by << 7, n0 = bx << 7;
  const int fr = lane & 15, kg = lane >> 4;
  const int rsub = lane >> 3;
  const int cb = (lane & 7) * 16;
  const int wr = (w >> 1) * 64, wc = (w & 1) * 64;

  float4v acc[4][4];
#pragma unroll
  for (int m = 0; m < 4; ++m)
#pragma unroll
    for (int n = 0; n < 4; ++n) acc[m][n] = (float4v)0.f;

  STAGE(Asl[0], Bsl[0], 0);
  __syncthreads();
  int cur = 0;
  for (int k0 = 0; k0 < K; k0 += 64){
    if (k0 + 64 < K) STAGE(Asl[cur ^ 1], Bsl[cur ^ 1], k0 + 64);
    MFMA_TILE(Asl[cur], Bsl[cur]);
    __syncthreads();
    cur ^= 1;
  }

#pragma unroll
  for (int m = 0; m < 4; ++m){
#pragma unroll
    for (int j = 0; j < 4; ++j){
      int row = m0 + wr + m * 16 + kg * 4 + j;
#pragma unroll
      for (int n = 0; n < 4; ++n){
        int col = n0 + wc + n * 16 + fr;
        float v = acc[m][n][j];
        size_t o = (size_t)row * N + col;
        if (mode == 0){
          v += bias[col];
          outA[o] = f2bf(v);
          outB[o] = f2bf(gelu_f(v));
        } else if (mode == 1){
          v += bias[col];
          if (outA) outA[o] = f2bf(v);
          if (outB) outB[o] = f2bf(W3[col] * dgelu_f(v));
        } else {
          v *= dgelu_f(bf2f(z1bf[o]));
          outA[o] = f2bf(v);
        }
      }
    }
  }
}

// split-K dy GEMM: part[ks][m][col<252] = dz1[m, ks*512:(ks+1)*512] @ W1bf[col, same]^T
// grid: (2, Mc/128, 4)
__global__ __launch_bounds__(256) void gemm_dy(
    const ushort_t* __restrict__ A, const ushort_t* __restrict__ BT,
    float* __restrict__ part, int Mc){
  __shared__ __align__(16) ushort_t Asl[2][128 * 64];
  __shared__ __align__(16) ushort_t Bsl[2][128 * 64];
  const int t = threadIdx.x, lane = t & 63, w = t >> 6;
  int bx = blockIdx.x, by = blockIdx.y;
  xcd_swizzle(gridDim.x, gridDim.y, bx, by);
  const int m0 = by << 7, n0 = bx << 7;
  const int K = HDIM;
  const int ks = blockIdx.z;
  const int kbeg = ks * (HDIM / 4), kend = kbeg + (HDIM / 4);
  const int fr = lane & 15, kg = lane >> 4;
  const int rsub = lane >> 3;
  const int cb = (lane & 7) * 16;
  const int wr = (w >> 1) * 64, wc = (w & 1) * 64;

  float4v acc[4][4];
#pragma unroll
  for (int m = 0; m < 4; ++m)
#pragma unroll
    for (int n = 0; n < 4; ++n) acc[m][n] = (float4v)0.f;

  STAGE(Asl[0], Bsl[0], kbeg);
  __syncthreads();
  int cur = 0;
  for (int k0 = kbeg; k0 < kend; k0 += 64){
    if (k0 + 64 < kend) STAGE(Asl[cur ^ 1], Bsl[cur ^ 1], k0 + 64);
    MFMA_TILE(Asl[cur], Bsl[cur]);
    __syncthreads();
    cur ^= 1;
  }

  float* pp = part + (size_t)ks * Mc * YDIM;
#pragma unroll
  for (int m = 0; m < 4; ++m){
#pragma unroll
    for (int j = 0; j < 4; ++j){
      int row = m0 + wr + m * 16 + kg * 4 + j;
#pragma unroll
      for (int n = 0; n < 4; ++n){
        int col = n0 + wc + n * 16 + fr;
        if (col < YDIM) pp[(size_t)row * YDIM + col] = acc[m][n][j];
      }
    }
  }
}

// ---------------- host ----------------
static inline char* carve(char*& p, size_t bytes){
  char* r = p; p += (bytes + 255) & ~(size_t)255; return r;
}

extern "C" void kernel_launch(void* const* d_in, const int* in_sizes, int n_in,
                              void* d_out, int out_size, void* d_ws, size_t ws_size,
                              hipStream_t stream){
  (void)in_sizes; (void)n_in; (void)out_size;
  const float* y_true  = (const float*)d_in[0];
  const float* cond    = (const float*)d_in[1];
  const int*   k_idx   = (const int*)d_in[2];
  const float* eps_pos = (const float*)d_in[3];
  const float* eps_neg = (const float*)d_in[4];
  const float* sel     = (const float*)d_in[5];
  const float* rv      = (const float*)d_in[6];
  const float* W1      = (const float*)d_in[7];
  const float* b1      = (const float*)d_in[8];
  const float* W2      = (const float*)d_in[9];
  const float* b2      = (const float*)d_in[10];
  const float* W3      = (const float*)d_in[11];
  const float* b3      = (const float*)d_in[12];
  const float* k_emb   = (const float*)d_in[13];

  char* p = (char*)d_ws;
  double* accs   = (double*)carve(p, 3 * sizeof(double));
  float* sigma_b = (float*)carve(p, (size_t)B_TOT * 4);
  float* e_pos   = (float*)carve(p, (size_t)B_TOT * 4);
  float* e_neg   = (float*)carve(p, (size_t)B_TOT * 4);
  ushort_t* W1bf = (ushort_t*)carve(p, (size_t)FEAT_REAL * HDIM * 2);
  ushort_t* W1T  = (ushort_t*)carve(p, (size_t)HDIM * FEATP * 2);
  ushort_t* W2bf = (ushort_t*)carve(p, (size_t)HDIM * HDIM * 2);
  ushort_t* W2T  = (ushort_t*)carve(p, (size_t)HDIM * HDIM * 2);
  size_t fixed = (size_t)(p - (char*)d_ws);

  // per-sample: feat(448*2) + 4 bf16 H-planes (z1bf,h1,z2bf,dz2) + yhat,yneg f32.
  // dz1 aliases h1 (h1 dead after z2-GEMM reads it);
  // dy partials (4 x 252 f32 = 4032B) alias dz2 (dead after dz1-GEMM reads it).
  const size_t per_sample = FEATP * 2 + 4 * HDIM * 2 + 2 * YDIM * 4; // 19296
  int Mc = B_TOT;
  while (Mc > 128 && fixed + (size_t)Mc * per_sample + 65536 > ws_size) Mc >>= 1;

  ushort_t* feat = (ushort_t*)carve(p, (size_t)Mc * FEATP * 2);
  ushort_t* z1bf = (ushort_t*)carve(p, (size_t)Mc * HDIM * 2);
  ushort_t* h1   = (ushort_t*)carve(p, (size_t)Mc * HDIM * 2);
  ushort_t* z2bf = (ushort_t*)carve(p, (size_t)Mc * HDIM * 2);
  ushort_t* dz2  = (ushort_t*)carve(p, (size_t)Mc * HDIM * 2);
  float* yhat = (float*)carve(p, (size_t)Mc * YDIM * 4);
  float* yneg = (float*)carve(p, (size_t)Mc * YDIM * 4);
  ushort_t* dz1 = h1;          // alias (liveness-checked)
  float* part   = (float*)dz2; // alias (liveness-checked)

  dim3 blk(256);
  k_zero_acc<<<1, 1, 0, stream>>>(accs);
  k_sigma<<<(B_TOT + 255) / 256, blk, 0, stream>>>(k_idx, sigma_b);
  k_cast<<<(FEAT_REAL * HDIM + 255) / 256, blk, 0, stream>>>(W1, W1bf, FEAT_REAL * HDIM);
  k_w1t<<<(HDIM * FEATP + 255) / 256, blk, 0, stream>>>(W1, W1T);
  k_cast<<<(HDIM * HDIM + 255) / 256, blk, 0, stream>>>(W2, W2bf, HDIM * HDIM);
  k_w2t<<<(HDIM * HDIM + 255) / 256, blk, 0, stream>>>(W2, W2T);

  auto G = [&](const ushort_t* Ap, const ushort_t* BTp, int N, int K, int mode,
               const float* biasp, const float* W3p, const ushort_t* z1p,
               ushort_t* oA, ushort_t* oB){
    gemm_bt<<<dim3(N / 128, Mc / 128), blk, 0, stream>>>(
        Ap, BTp, N, K, mode, biasp, W3p, z1p, oA, oB);
  };
  auto Gdy = [&](){
    gemm_dy<<<dim3(2, Mc / 128, 4), blk, 0, stream>>>(dz1, W1bf, part, Mc);
  };

  int nCh = B_TOT / Mc;
  for (int c = 0; c < nCh; ++c){
    int b0 = c * Mc;
    k_feat_static<<<(Mc * 196 + 255) / 256, blk, 0, stream>>>(
        cond + (size_t)b0 * CELLS, k_emb, k_idx + b0, feat, Mc);

    // ---- positive branch
    k_noise<<<(Mc * CELLS + 255) / 256, blk, 0, stream>>>(
        y_true + (size_t)b0 * YDIM, eps_pos + (size_t)b0 * YDIM, sigma_b + b0, yhat, feat, Mc);
    G(feat, W1T, HDIM, FEATP, 0, b1, nullptr, nullptr, z1bf, h1);
    G(h1, W2T, HDIM, HDIM, 1, b2, W3, nullptr, z2bf, dz2);
    k_energy<<<(Mc + 3) / 4, blk, 0, stream>>>(z2bf, W3, b3, e_pos + b0, Mc);
    G(dz2, W2bf, HDIM, HDIM, 2, nullptr, nullptr, z1bf, dz1, nullptr);
    Gdy();
    k_mse<<<512, blk, 0, stream>>>(part, yhat, y_true + (size_t)b0 * YDIM, sigma_b + b0, accs, Mc);

    // ---- negative branch
    k_makeneg<<<(Mc * 64 + 255) / 256, blk, 0, stream>>>(y_true, sel, rv, yneg, feat, b0, Mc);
    for (int r = 0; r < 5; ++r){
      G(feat, W1T, HDIM, FEATP, 0, b1, nullptr, nullptr, z1bf, h1);
      G(h1, W2T, HDIM, HDIM, 1, b2, W3, nullptr, nullptr, dz2);
      G(dz2, W2bf, HDIM, HDIM, 2, nullptr, nullptr, z1bf, dz1, nullptr);
      Gdy();
      k_upd<<<(Mc * YDIM + 255) / 256, blk, 0, stream>>>(part, yneg, feat, Mc);
    }
    k_noise<<<(Mc * CELLS + 255) / 256, blk, 0, stream>>>(
        yneg, eps_neg + (size_t)b0 * YDIM, sigma_b + b0, yhat, feat, Mc);
    G(feat, W1T, HDIM, FEATP, 0, b1, nullptr, nullptr, z1bf, h1);
    G(h1, W2T, HDIM, HDIM, 1, b2, W3, nullptr, z2bf, nullptr);
    k_energy<<<(Mc + 3) / 4, blk, 0, stream>>>(z2bf, W3, b3, e_neg + b0, Mc);
  }

  k_contrast<<<64, blk, 0, stream>>>(e_pos, e_neg, accs);
  k_finalize<<<1, 1, 0, stream>>>(accs, (float*)d_out);
}